// Round 16
// baseline (177.267 us; speedup 1.0000x reference)
//
#include <hip/hip_runtime.h>

#define NROWS 8192
#define NSPLIT 8
#define JT (NROWS / NSPLIT)  // 1024 j's per split
#define NITER (JT / 64)      // 16
#define L2E 1.4426950408889634f

typedef __attribute__((ext_vector_type(4))) float f32x4;
typedef __attribute__((ext_vector_type(8))) __bf16 bf16x8;
typedef __attribute__((ext_vector_type(4))) unsigned int u32x4;

__device__ __forceinline__ unsigned short f2bf(float x) {
  unsigned u = __float_as_uint(x);
  u += 0x7fffu + ((u >> 16) & 1u);
  return (unsigned short)(u >> 16);
}

// ---------------------------------------------------------------------------
// Kernel S: PURE-READ STREAM MEASUREMENT. Reads 256 MiB (= |adj|) of d_ws
// scratch as int4 grid-stride (the canonical coalesced pattern), wave-XOR
// reduce (keeps every lane's loads live), lane-0 store (~32 KB total).
// ~16 VGPR -> 32 waves/CU. The dur_us delta vs the R7 baseline (118.3 us)
// isolates the platform's achievable pure-read rate for an adj-sized sweep.
// ---------------------------------------------------------------------------
__global__ __launch_bounds__(256) void k_stream(
    const int4* __restrict__ srcbuf, int4* __restrict__ sink, int n4) {
  int tid = blockIdx.x * 256 + threadIdx.x;
  int stride = gridDim.x * 256;
  int ax = 0, ay = 0, az = 0, aw = 0;
  for (int i = tid; i < n4; i += stride) {
    int4 v = srcbuf[i];
    ax ^= v.x; ay ^= v.y; az ^= v.z; aw ^= v.w;
  }
#pragma unroll
  for (int d = 32; d; d >>= 1) {
    ax ^= __shfl_xor(ax, d);
    ay ^= __shfl_xor(ay, d);
    az ^= __shfl_xor(az, d);
    aw ^= __shfl_xor(aw, d);
  }
  if ((threadIdx.x & 63) == 0) {
    int w = blockIdx.x * 4 + (threadIdx.x >> 6);
    sink[w] = make_int4(ax, ay, az, aw);
  }
}

// ---------------------------------------------------------------------------
// Kernel A: Wh = h@W (stored bf16 in MFMA-B-fragment order), src=Wh@a1, dst=Wh@a2
// src/dst pre-scaled by log2(e) so downstream works in exp2 domain.
// Fragment layout: slot (jc, nt, lane, e) holds Wh[j = 32*jc + 8*(lane>>4) + e][nt*16 + (lane&15)]
// ---------------------------------------------------------------------------
__global__ __launch_bounds__(256) void k_prep(
    const float* __restrict__ h, const float* __restrict__ W,
    const float* __restrict__ a, unsigned short* __restrict__ WhB,
    float* __restrict__ src, float* __restrict__ dst) {
  int i = blockIdx.x * 4 + (threadIdx.x >> 6);  // row
  int lane = threadIdx.x & 63;                  // feature
  const float* hrow = h + (size_t)i * 256;
  float s = 0.f;
#pragma unroll 4
  for (int k = 0; k < 256; k += 4) {
    float4 hv = *(const float4*)(hrow + k);
    s = fmaf(hv.x, W[(k + 0) * 64 + lane], s);
    s = fmaf(hv.y, W[(k + 1) * 64 + lane], s);
    s = fmaf(hv.z, W[(k + 2) * 64 + lane], s);
    s = fmaf(hv.w, W[(k + 3) * 64 + lane], s);
  }
  int nt = lane >> 4, c = lane & 15;
  int gi = (i >> 3) & 3, e = i & 7;
  int idx = ((((i >> 5) * 4 + nt) * 64) + c + 16 * gi) * 8 + e;
  WhB[idx] = f2bf(s);
  float v1 = s * a[lane];
  float v2 = s * a[64 + lane];
#pragma unroll
  for (int d = 32; d; d >>= 1) {
    v1 += __shfl_xor(v1, d);
    v2 += __shfl_xor(v2, d);
  }
  if (lane == 0) {
    src[i] = v1 * L2E;
    dst[i] = v2 * L2E;
  }
}

// ---------------------------------------------------------------------------
// Kernel A2: dmax = max_j dst[j]  (global scalar; 1 block)
// ---------------------------------------------------------------------------
__global__ __launch_bounds__(256) void k_dmax(
    const float* __restrict__ dst, float* __restrict__ dmax) {
  __shared__ float red[4];
  float v = -INFINITY;
  for (int i = threadIdx.x; i < NROWS; i += 256) v = fmaxf(v, dst[i]);
#pragma unroll
  for (int d = 32; d; d >>= 1) v = fmaxf(v, __shfl_xor(v, d));
  if ((threadIdx.x & 63) == 0) red[threadIdx.x >> 6] = v;
  __syncthreads();
  if (threadIdx.x == 0)
    *dmax = fmaxf(fmaxf(red[0], red[1]), fmaxf(red[2], red[3]));
}

// ---------------------------------------------------------------------------
// Kernel B (FUSED, R7 baseline — unchanged): in-wave ballot-pack of adj +
// masked-softmax + PV. One wave = one (16-row M-tile, split) task.
// ---------------------------------------------------------------------------
__global__ __launch_bounds__(256, 4) void k_attn(
    const int* __restrict__ adj, const unsigned short* __restrict__ WhB,
    const float* __restrict__ src, const float* __restrict__ dst,
    const float* __restrict__ dmax,
    float* __restrict__ pl, float* __restrict__ pacc) {
  __shared__ float ldst[JT];
  int task = blockIdx.x * 4 + (threadIdx.x >> 6);  // 0 .. 512*NSPLIT-1
  int sp = task >> 9;                              // split (same for whole block)
  int mt = task & 511;                             // M-tile index
  int lane = threadIdx.x & 63;
  int r = lane & 15;  // row within tile / C col
  int g = lane >> 4;  // k-slot group
  int row0 = mt * 16;
  int jbase = sp * JT;

  // stage this split's dst slice to LDS (block-shared)
  for (int k = threadIdx.x; k < JT; k += 256) ldst[k] = dst[jbase + k];
  __syncthreads();

  // ---- Phase 1: ballot-pack 16 rows x 1024 cols into 4 u64 regs/lane ----
  unsigned long long mk0 = 0, mk1 = 0, mk2 = 0, mk3 = 0;
  {
    const int* abase = adj + (size_t)row0 * NROWS + jbase + lane;
#pragma unroll
    for (int rr = 0; rr < 16; ++rr) {
      const int* rp = abase + (size_t)rr * NROWS;
#pragma unroll
      for (int ch = 0; ch < 16; ++ch) {
        int v = rp[ch * 64];
        unsigned long long bal = __ballot(v > 0);
        const int holder = ((ch & 3) << 4) + rr;
        if ((ch >> 2) == 0) mk0 = (lane == holder) ? bal : mk0;
        if ((ch >> 2) == 1) mk1 = (lane == holder) ? bal : mk1;
        if ((ch >> 2) == 2) mk2 = (lane == holder) ? bal : mk2;
        if ((ch >> 2) == 3) mk3 = (lane == holder) ? bal : mk3;
      }
    }
  }

  float srcr = src[row0 + r];
  float vB = srcr + *dmax;
  float Mi = fmaxf(vB, 0.2f * vB);  // upper bound on this row's scores

  float lrow = 0.f;
  f32x4 acc[4] = {f32x4{0.f, 0.f, 0.f, 0.f}, f32x4{0.f, 0.f, 0.f, 0.f},
                  f32x4{0.f, 0.f, 0.f, 0.f}, f32x4{0.f, 0.f, 0.f, 0.f}};
  const bf16x8* Bfr = (const bf16x8*)WhB;

  // ---- Phase 2: bitmask softmax + PV ----
#pragma unroll
  for (int it = 0; it < NITER; ++it) {
    const int jb = it * 64;

    // mask(r, it): one cross-lane fetch, replaces any adj memory access
    unsigned long long pw;
    if ((it >> 2) == 0) pw = __shfl(mk0, ((it & 3) << 4) + r);
    if ((it >> 2) == 1) pw = __shfl(mk1, ((it & 3) << 4) + r);
    if ((it >> 2) == 2) pw = __shfl(mk2, ((it & 3) << 4) + r);
    if ((it >> 2) == 3) pw = __shfl(mk3, ((it & 3) << 4) + r);

    // B(t): L2-hot fragment loads (1 KB coalesced per instr)
    int jc = (jbase + jb) >> 5;
    const bf16x8* bp = Bfr + (size_t)jc * 256 + lane;
    bf16x8 b0 = bp[0];
    bf16x8 b1 = bp[64];
    bf16x8 b2 = bp[128];
    bf16x8 b3 = bp[192];
    bf16x8 b4 = bp[256];
    bf16x8 b5 = bp[320];
    bf16x8 b6 = bp[384];
    bf16x8 b7 = bp[448];

    // dst from LDS (4 addresses per wave -> broadcast, conflict-free)
    const float* dl = ldst + jb + 8 * g;
    float4 d0 = *(const float4*)(dl);
    float4 d1 = *(const float4*)(dl + 4);
    float4 d2 = *(const float4*)(dl + 32);
    float4 d3 = *(const float4*)(dl + 36);

    // bits for cols jb+8g+e (lo) and jb+32+8g+e (hi), e = bit index 0..7
    unsigned lo = (unsigned)(pw >> (8 * g));
    unsigned hi = (unsigned)(pw >> (32 + 8 * g));

    float p[16];
#define PE(P, BIT, DD)                    \
  {                                       \
    float v_ = srcr + (DD);               \
    v_ = fmaxf(v_, 0.2f * v_);            \
    float e_ = exp2f(v_ - Mi);            \
    (P) = (BIT) ? e_ : 0.f;               \
  }
    PE(p[0], lo & 1u, d0.x)   PE(p[1], lo & 2u, d0.y)
    PE(p[2], lo & 4u, d0.z)   PE(p[3], lo & 8u, d0.w)
    PE(p[4], lo & 16u, d1.x)  PE(p[5], lo & 32u, d1.y)
    PE(p[6], lo & 64u, d1.z)  PE(p[7], lo & 128u, d1.w)
    PE(p[8], hi & 1u, d2.x)   PE(p[9], hi & 2u, d2.y)
    PE(p[10], hi & 4u, d2.z)  PE(p[11], hi & 8u, d2.w)
    PE(p[12], hi & 16u, d3.x) PE(p[13], hi & 32u, d3.y)
    PE(p[14], hi & 64u, d3.z) PE(p[15], hi & 128u, d3.w)
#undef PE

    unsigned q[8];
#pragma unroll
    for (int t = 0; t < 16; t += 2) {
      lrow += p[t] + p[t + 1];
      unsigned qq;
      asm("v_cvt_pk_bf16_f32 %0, %1, %2" : "=v"(qq) : "v"(p[t]), "v"(p[t + 1]));
      q[t >> 1] = qq;
    }
    u32x4 qv0 = {q[0], q[1], q[2], q[3]};
    u32x4 qv1 = {q[4], q[5], q[6], q[7]};
    bf16x8 A0 = __builtin_bit_cast(bf16x8, qv0);
    bf16x8 A1 = __builtin_bit_cast(bf16x8, qv1);

    __builtin_amdgcn_s_setprio(1);
    acc[0] = __builtin_amdgcn_mfma_f32_16x16x32_bf16(A0, b0, acc[0], 0, 0, 0);
    acc[1] = __builtin_amdgcn_mfma_f32_16x16x32_bf16(A0, b1, acc[1], 0, 0, 0);
    acc[2] = __builtin_amdgcn_mfma_f32_16x16x32_bf16(A0, b2, acc[2], 0, 0, 0);
    acc[3] = __builtin_amdgcn_mfma_f32_16x16x32_bf16(A0, b3, acc[3], 0, 0, 0);
    acc[0] = __builtin_amdgcn_mfma_f32_16x16x32_bf16(A1, b4, acc[0], 0, 0, 0);
    acc[1] = __builtin_amdgcn_mfma_f32_16x16x32_bf16(A1, b5, acc[1], 0, 0, 0);
    acc[2] = __builtin_amdgcn_mfma_f32_16x16x32_bf16(A1, b6, acc[2], 0, 0, 0);
    acc[3] = __builtin_amdgcn_mfma_f32_16x16x32_bf16(A1, b7, acc[3], 0, 0, 0);
    __builtin_amdgcn_s_setprio(0);
  }

  // row-sum of l across the 4 g-groups (lanes r, r+16, r+32, r+48)
  lrow += __shfl_xor(lrow, 16);
  lrow += __shfl_xor(lrow, 32);
  if (lane < 16) pl[sp * NROWS + row0 + lane] = lrow;
#pragma unroll
  for (int nt = 0; nt < 4; nt++)
#pragma unroll
    for (int q2 = 0; q2 < 4; q2++)
      pacc[((size_t)sp * NROWS + row0 + 4 * g + q2) * 64 + nt * 16 + r] = acc[nt][q2];
}

// ---------------------------------------------------------------------------
// Kernel C: combine = plain sums (all splits share the same reference Mi).
// ---------------------------------------------------------------------------
__global__ __launch_bounds__(256) void k_comb(
    const float* __restrict__ pl, const float* __restrict__ pacc,
    float* __restrict__ out) {
  int t = blockIdx.x * 256 + threadIdx.x;
  int row = t >> 6, f = t & 63;
  float L = 0.f, o = 0.f;
#pragma unroll
  for (int s2 = 0; s2 < NSPLIT; s2++) {
    L += pl[s2 * NROWS + row];
    o += pacc[((size_t)s2 * NROWS + row) * 64 + f];
  }
  out[t] = o / L;
}

extern "C" void kernel_launch(void* const* d_in, const int* in_sizes, int n_in,
                              void* d_out, int out_size, void* d_ws, size_t ws_size,
                              hipStream_t stream) {
  const float* h = (const float*)d_in[0];
  const float* W = (const float*)d_in[1];
  const float* a = (const float*)d_in[2];
  const int* adj = (const int*)d_in[3];
  float* out = (float*)d_out;

  char* ws = (char*)d_ws;
  unsigned short* WhB = (unsigned short*)ws;           // 1 MB
  float* src = (float*)(ws + 0x100000);                // 32 KB
  float* dst = (float*)(ws + 0x108000);                // 32 KB
  float* dmax = (float*)(ws + 0x110000);               // 256 B
  float* pl = (float*)(ws + 0x110100);                 // 256 KB
  float* pacc = (float*)(ws + 0x150100);               // 16 MB
  int4* sink = (int4*)(ws + 0x1200000);                // 128 KB sink

  // stream source: untouched scratch far from live buffers; 256 MiB = |adj|
  size_t half = ws_size / 2;
  size_t src_off = (half + 255) & ~(size_t)255;
  size_t avail = ws_size - src_off;
  size_t sbytes = avail < ((size_t)256 << 20) ? (avail & ~(size_t)4095)
                                              : ((size_t)256 << 20);
  const int4* sbuf = (const int4*)(ws + src_off);
  int n4 = (int)(sbytes / 16);

  hipLaunchKernelGGL(k_stream, dim3(2048), dim3(256), 0, stream, sbuf, sink, n4);
  hipLaunchKernelGGL(k_prep, dim3(NROWS / 4), dim3(256), 0, stream, h, W, a, WhB, src, dst);
  hipLaunchKernelGGL(k_dmax, dim3(1), dim3(256), 0, stream, dst, dmax);
  hipLaunchKernelGGL(k_attn, dim3(512 * NSPLIT / 4), dim3(256), 0, stream,
                     adj, WhB, src, dst, dmax, pl, pacc);
  hipLaunchKernelGGL(k_comb, dim3(NROWS * 64 / 256), dim3(256), 0, stream, pl, pacc, out);
}

// Round 17
// 136.042 us; speedup vs baseline: 1.3030x; 1.3030x over previous
//
#include <hip/hip_runtime.h>

#define NROWS 8192
#define NSPLIT 16
#define JT (NROWS / NSPLIT)  // 512 j's per split
#define L2E 1.4426950408889634f

typedef __attribute__((ext_vector_type(4))) float f32x4;
typedef __attribute__((ext_vector_type(8))) __bf16 bf16x8;
typedef __attribute__((ext_vector_type(4))) unsigned int u32x4;

__device__ __forceinline__ unsigned short f2bf(float x) {
  unsigned u = __float_as_uint(x);
  u += 0x7fffu + ((u >> 16) & 1u);
  return (unsigned short)(u >> 16);
}

// ---------------------------------------------------------------------------
// Kernel A: Wh = h@W (bf16, MFMA-B-fragment order), src=Wh@a1, dst=Wh@a2
// (exp2 domain). Fragment layout: slot (jc, nt, lane, e) holds
// Wh[j = 32*jc + 8*(lane>>4) + e][nt*16 + (lane&15)]
// ---------------------------------------------------------------------------
__global__ __launch_bounds__(256) void k_prep(
    const float* __restrict__ h, const float* __restrict__ W,
    const float* __restrict__ a, unsigned short* __restrict__ WhB,
    float* __restrict__ src, float* __restrict__ dst) {
  int i = blockIdx.x * 4 + (threadIdx.x >> 6);  // row
  int lane = threadIdx.x & 63;                  // feature
  const float* hrow = h + (size_t)i * 256;
  float s = 0.f;
#pragma unroll 4
  for (int k = 0; k < 256; k += 4) {
    float4 hv = *(const float4*)(hrow + k);
    s = fmaf(hv.x, W[(k + 0) * 64 + lane], s);
    s = fmaf(hv.y, W[(k + 1) * 64 + lane], s);
    s = fmaf(hv.z, W[(k + 2) * 64 + lane], s);
    s = fmaf(hv.w, W[(k + 3) * 64 + lane], s);
  }
  int nt = lane >> 4, c = lane & 15;
  int gi = (i >> 3) & 3, e = i & 7;
  int idx = ((((i >> 5) * 4 + nt) * 64) + c + 16 * gi) * 8 + e;
  WhB[idx] = f2bf(s);
  float v1 = s * a[lane];
  float v2 = s * a[64 + lane];
#pragma unroll
  for (int d = 32; d; d >>= 1) {
    v1 += __shfl_xor(v1, d);
    v2 += __shfl_xor(v2, d);
  }
  if (lane == 0) {
    src[i] = v1 * L2E;
    dst[i] = v2 * L2E;
  }
}

// ---------------------------------------------------------------------------
// Kernel A2: dmax = max_j dst[j]  (global scalar; 1 block)
// ---------------------------------------------------------------------------
__global__ __launch_bounds__(256) void k_dmax(
    const float* __restrict__ dst, float* __restrict__ dmax) {
  __shared__ float red[4];
  float v = -INFINITY;
  for (int i = threadIdx.x; i < NROWS; i += 256) v = fmaxf(v, dst[i]);
#pragma unroll
  for (int d = 32; d; d >>= 1) v = fmaxf(v, __shfl_xor(v, d));
  if ((threadIdx.x & 63) == 0) red[threadIdx.x >> 6] = v;
  __syncthreads();
  if (threadIdx.x == 0)
    *dmax = fmaxf(fmaxf(red[0], red[1]), fmaxf(red[2], red[3]));
}

// ---------------------------------------------------------------------------
// Kernel P: adj -> bitmask pack in the MEASURED-FAST k_stream shape
// (R16: grid-stride int4 read = 4.5 TB/s; R14's 2-loads-per-wave shape =
// ~2.8 TB/s from per-wave overhead). 2048 blocks x 256 thr, ~20 VGPR ->
// 32 waves/CU; 32 grid-stride iterations per wave; chip-wide sweep is
// contiguous like k_stream. Per 1 KB chunk (row, gq): one int4 load,
// 4 ballots, lanes 0-3 store 32 B.
// Layout: packed[(row*32 + gq)*4 + c], bit l <-> col gq*256 + 4*l + c.
// ---------------------------------------------------------------------------
#define NCHUNK (NROWS * 32)  // 262144 chunks of 256 cols
__global__ __launch_bounds__(256) void k_pack(
    const int* __restrict__ adj, unsigned long long* __restrict__ packed) {
  int wid = blockIdx.x * 4 + (threadIdx.x >> 6);  // 0..8191
  int lane = threadIdx.x & 63;
  for (int cid = wid; cid < NCHUNK; cid += 8192) {
    const int4* bp = (const int4*)(adj + (size_t)cid * 256);
    int4 v = bp[lane];  // cols 4*lane .. 4*lane+3 of this chunk
    unsigned long long b0 = __ballot(v.x > 0);
    unsigned long long b1 = __ballot(v.y > 0);
    unsigned long long b2 = __ballot(v.z > 0);
    unsigned long long b3 = __ballot(v.w > 0);
    if (lane < 4) {
      unsigned long long val = (lane == 0) ? b0 : (lane == 1) ? b1
                             : (lane == 2) ? b2 : b3;
      packed[(size_t)cid * 4 + lane] = val;
    }
  }
}

// ---------------------------------------------------------------------------
// Kernel B: masked-softmax + PV from the packed bitmask (R14 structure,
// packed indexing adjusted to row-major [row][gq][c]). One wave = one
// (16-row tile, split). NO transcendentals in the loop:
// 2^(lrelu(x)) = max(2^x, 2^(x/5)) factors as max(Ai*Bj, Ci*Dj);
// absolute bound Mi = lrelu(src_i+dmax). lb(256,5) -> ~20 waves/CU.
// ---------------------------------------------------------------------------
__global__ __launch_bounds__(256, 5) void k_attn(
    const unsigned long long* __restrict__ packed,
    const unsigned short* __restrict__ WhB,
    const float* __restrict__ src, const float* __restrict__ dst,
    const float* __restrict__ dmax,
    float* __restrict__ pl, float* __restrict__ pacc) {
  __shared__ float2 ldst2[JT];
  int task = blockIdx.x * 4 + (threadIdx.x >> 6);  // 0 .. 8191
  int sp = task >> 9;                              // split 0..15
  int mt = task & 511;                             // M-tile index
  int lane = threadIdx.x & 63;
  int r = lane & 15;  // row within tile / C col
  int g = lane >> 4;  // k-slot group
  int row0 = mt * 16;
  int jbase = sp * JT;

  // stage (2^dst, 2^(dst/5)) for this split's cols
  for (int k = threadIdx.x; k < JT; k += 256) {
    float dj = dst[jbase + k];
    ldst2[k] = make_float2(exp2f(dj), exp2f(0.2f * dj));
  }
  __syncthreads();

  float srcr = src[row0 + r];
  float vB = srcr + *dmax;
  float Mi = fmaxf(vB, 0.2f * vB);  // upper bound on this row's scores
  float Ai = exp2f(srcr - Mi);
  float Ci = exp2f(0.2f * srcr - Mi);

  float lrow = 0.f;
  f32x4 acc[4] = {f32x4{0.f, 0.f, 0.f, 0.f}, f32x4{0.f, 0.f, 0.f, 0.f},
                  f32x4{0.f, 0.f, 0.f, 0.f}, f32x4{0.f, 0.f, 0.f, 0.f}};
  const bf16x8* Bfr = (const bf16x8*)WhB;

#define PE(P, BIT, BV, DV)                         \
  {                                                \
    float e_ = fmaxf(Ai * (BV), Ci * (DV));        \
    (P) = ((unsigned)(BIT)&1u) ? e_ : 0.f;         \
  }
  // one 32-col half: 4 B-frags + 16 LDS floats + 8 PE -> pack -> 4 MFMA
#define HALF(JC, A0_, A1_, A2_, A3_, DOFF)                                 \
  {                                                                        \
    const bf16x8* bp = Bfr + (size_t)(JC) * 256 + lane;                    \
    bf16x8 b0 = bp[0];                                                     \
    bf16x8 b1 = bp[64];                                                    \
    bf16x8 b2 = bp[128];                                                   \
    bf16x8 b3 = bp[192];                                                   \
    const float4* dlp = (const float4*)(ldst2 + (DOFF));                   \
    float4 d0 = dlp[0], d1 = dlp[1], d2 = dlp[2], d3 = dlp[3];             \
    float p0, p1, p2, p3, p4, p5, p6, p7;                                  \
    PE(p0, (A0_), d0.x, d0.y)      PE(p1, (A1_), d0.z, d0.w)               \
    PE(p2, (A2_), d1.x, d1.y)      PE(p3, (A3_), d1.z, d1.w)               \
    PE(p4, (A0_) >> 1, d2.x, d2.y) PE(p5, (A1_) >> 1, d2.z, d2.w)          \
    PE(p6, (A2_) >> 1, d3.x, d3.y) PE(p7, (A3_) >> 1, d3.z, d3.w)          \
    lrow += ((p0 + p1) + (p2 + p3)) + ((p4 + p5) + (p6 + p7));             \
    unsigned q0, q1, q2, q3;                                               \
    asm("v_cvt_pk_bf16_f32 %0, %1, %2" : "=v"(q0) : "v"(p0), "v"(p1));     \
    asm("v_cvt_pk_bf16_f32 %0, %1, %2" : "=v"(q1) : "v"(p2), "v"(p3));     \
    asm("v_cvt_pk_bf16_f32 %0, %1, %2" : "=v"(q2) : "v"(p4), "v"(p5));     \
    asm("v_cvt_pk_bf16_f32 %0, %1, %2" : "=v"(q3) : "v"(p6), "v"(p7));     \
    u32x4 qv = {q0, q1, q2, q3};                                           \
    bf16x8 Af = __builtin_bit_cast(bf16x8, qv);                            \
    __builtin_amdgcn_s_setprio(1);                                         \
    acc[0] = __builtin_amdgcn_mfma_f32_16x16x32_bf16(Af, b0, acc[0], 0, 0, 0); \
    acc[1] = __builtin_amdgcn_mfma_f32_16x16x32_bf16(Af, b1, acc[1], 0, 0, 0); \
    acc[2] = __builtin_amdgcn_mfma_f32_16x16x32_bf16(Af, b2, acc[2], 0, 0, 0); \
    acc[3] = __builtin_amdgcn_mfma_f32_16x16x32_bf16(Af, b3, acc[3], 0, 0, 0); \
    __builtin_amdgcn_s_setprio(0);                                         \
  }

#pragma unroll 1
  for (int sg = 0; sg < 2; ++sg) {
    int seg = sp * 2 + sg;
    // 4 words (c=0..3) for this lane's row: 32 B (4-way lane broadcast)
    const ulonglong2* pwp =
        (const ulonglong2*)(packed + ((size_t)(row0 + r) * 32 + seg) * 4);
    ulonglong2 wa = pwp[0];
    ulonglong2 wb = pwp[1];
    unsigned long long u0 = wa.x >> (2 * g);
    unsigned long long u1 = wa.y >> (2 * g);
    unsigned long long u2 = wb.x >> (2 * g);
    unsigned long long u3 = wb.y >> (2 * g);
#pragma unroll
    for (int inner = 0; inner < 4; ++inner) {
      int it = sg * 4 + inner;
      int jb = it * 64;
      unsigned long long a0 = u0 >> (inner * 16);
      unsigned long long a1 = u1 >> (inner * 16);
      unsigned long long a2 = u2 >> (inner * 16);
      unsigned long long a3 = u3 >> (inner * 16);
      unsigned long long h0 = a0 >> 8, h1 = a1 >> 8, h2 = a2 >> 8, h3 = a3 >> 8;
      int jc = sp * 16 + 2 * it;
      HALF(jc, a0, a1, a2, a3, jb + 8 * g)
      HALF(jc + 1, h0, h1, h2, h3, jb + 32 + 8 * g)
    }
  }
#undef HALF
#undef PE

  // row-sum of l across the 4 g-groups (lanes r, r+16, r+32, r+48)
  lrow += __shfl_xor(lrow, 16);
  lrow += __shfl_xor(lrow, 32);
  if (lane < 16) pl[sp * NROWS + row0 + lane] = lrow;
  // coalesced pacc: [sp][mt][nt][q][lane], lane = g*16+r
#pragma unroll
  for (int nt = 0; nt < 4; nt++)
#pragma unroll
    for (int q2 = 0; q2 < 4; q2++)
      pacc[((((size_t)sp * 512 + mt) * 4 + nt) * 4 + q2) * 64 + lane] = acc[nt][q2];
}

// ---------------------------------------------------------------------------
// Kernel C: combine = plain sums (all splits share the same reference Mi).
// pacc layout: [sp][mt][nt][q][g*16+r]; row = mt*16 + 4g+q, f = nt*16+r.
// ---------------------------------------------------------------------------
__global__ __launch_bounds__(256) void k_comb(
    const float* __restrict__ pl, const float* __restrict__ pacc,
    float* __restrict__ out) {
  int t = blockIdx.x * 256 + threadIdx.x;
  int row = t >> 6, f = t & 63;
  int mt = row >> 4, rem = row & 15, g = rem >> 2, q = rem & 3;
  int nt = f >> 4, r = f & 15;
  size_t base = ((((size_t)mt) * 4 + nt) * 4 + q) * 64 + g * 16 + r;
  float L = 0.f, o = 0.f;
#pragma unroll
  for (int s2 = 0; s2 < NSPLIT; s2++) {
    L += pl[s2 * NROWS + row];
    o += pacc[(size_t)s2 * (512 * 4 * 4 * 64) + base];
  }
  out[t] = o / L;
}

extern "C" void kernel_launch(void* const* d_in, const int* in_sizes, int n_in,
                              void* d_out, int out_size, void* d_ws, size_t ws_size,
                              hipStream_t stream) {
  const float* h = (const float*)d_in[0];
  const float* W = (const float*)d_in[1];
  const float* a = (const float*)d_in[2];
  const int* adj = (const int*)d_in[3];
  float* out = (float*)d_out;

  char* ws = (char*)d_ws;
  unsigned short* WhB = (unsigned short*)ws;                           // 1 MB
  float* src = (float*)(ws + 0x100000);                                // 32 KB
  float* dst = (float*)(ws + 0x108000);                                // 32 KB
  float* dmax = (float*)(ws + 0x110000);                               // 256 B
  float* pl = (float*)(ws + 0x110100);                                 // 512 KB
  float* pacc = (float*)(ws + 0x190100);                               // 32 MB
  unsigned long long* packed = (unsigned long long*)(ws + 0x2200000);  // 8 MB

  hipLaunchKernelGGL(k_pack, dim3(2048), dim3(256), 0, stream, adj, packed);
  hipLaunchKernelGGL(k_prep, dim3(NROWS / 4), dim3(256), 0, stream, h, W, a, WhB, src, dst);
  hipLaunchKernelGGL(k_dmax, dim3(1), dim3(256), 0, stream, dst, dmax);
  hipLaunchKernelGGL(k_attn, dim3(2048), dim3(256), 0, stream,
                     packed, WhB, src, dst, dmax, pl, pacc);
  hipLaunchKernelGGL(k_comb, dim3(NROWS * 64 / 256), dim3(256), 0, stream, pl, pacc, out);
}